// Round 3
// baseline (7946.957 us; speedup 1.0000x reference)
//
#include <hip/hip_runtime.h>
#include <hip/hip_bf16.h>
#include <math.h>

#define D_MODEL 192
#define D_INNER 384
#define D_STATE 16
#define DT_RANK 12
#define DEPTH   24
#define SEQL    257
#define BATCH   32
#define NTOK    (BATCH*SEQL)   // 8224

typedef unsigned short ushort_t;
using bf16x8 = __attribute__((ext_vector_type(8))) short;
using f32x4  = __attribute__((ext_vector_type(4))) float;

__device__ __forceinline__ ushort_t f2b(float f) {
    __hip_bfloat16 h = __float2bfloat16(f);
    return reinterpret_cast<ushort_t&>(h);
}
__device__ __forceinline__ float b2f(ushort_t u) {
    __hip_bfloat16 h;
    reinterpret_cast<ushort_t&>(h) = u;
    return __bfloat162float(h);
}

// ---------------- fp32 -> bf16 conversion ----------------
__global__ __launch_bounds__(256) void convert_k(const float* __restrict__ in, ushort_t* __restrict__ out, int n) {
    int i = (blockIdx.x * 256 + threadIdx.x) * 4;
    if (i + 3 < n) {
        float4 v = *(const float4*)(in + i);
        ushort4 o;
        o.x = f2b(v.x); o.y = f2b(v.y); o.z = f2b(v.z); o.w = f2b(v.w);
        *(ushort4*)(out + i) = o;
    } else {
        for (int j = i; j < n; j++) out[j] = f2b(in[j]);
    }
}

// ---------------- patch rearrange: x (B,3,256,256) -> Apatch bf16 (B*256, 768) ----------------
__global__ __launch_bounds__(256) void rearrange_k(const float* __restrict__ x, ushort_t* __restrict__ Ap) {
    size_t i = (size_t)blockIdx.x * 256 + threadIdx.x;
    const size_t total = (size_t)8192 * 768 / 4;
    if (i >= total) return;
    size_t o = i * 4;
    int bt  = (int)(o / 768);
    int rem = (int)(o % 768);
    int c  = rem >> 8;
    int r2 = rem & 255;
    int pi = r2 >> 4;
    int pj = r2 & 15;
    int b = bt >> 8;
    int t = bt & 255;
    int ph = t >> 4, pw = t & 15;
    size_t src = (((size_t)(b * 3 + c) * 256) + (size_t)(ph * 16 + pi)) * 256 + (pw * 16 + pj);
    float4 v = *(const float4*)(x + src);
    ushort4 ov;
    ov.x = f2b(v.x); ov.y = f2b(v.y); ov.z = f2b(v.z); ov.w = f2b(v.w);
    *(ushort4*)(Ap + o) = ov;
}

// ---------------- assemble: insert cls token, add patch bias + pos embed ----------------
__global__ __launch_bounds__(192) void assemble_k(const float* __restrict__ P, const float* __restrict__ pb,
                                                  const float* __restrict__ cls, const float* __restrict__ pos,
                                                  float* __restrict__ hb) {
    int o = threadIdx.x;
    int l = blockIdx.x;
    int b = blockIdx.y;
    float v;
    if (l == 128) {
        v = cls[o];
    } else {
        int t = (l < 128) ? l : l - 1;
        v = P[((size_t)b * 256 + t) * 192 + o] + pb[o];
    }
    hb[((size_t)b * SEQL + l) * 192 + o] = v + pos[l * 192 + o];
}

// ---------------- fused add + RMSNorm ----------------
template<int FINAL>
__global__ __launch_bounds__(192) void addnorm_k(float* res, const float* __restrict__ h,
                                                 const float* __restrict__ w, void* __restrict__ outp) {
    int row = blockIdx.x;
    int t = threadIdx.x;
    size_t idx = (size_t)row * 192 + t;
    float r = res[idx] + h[idx];
    if (!FINAL) res[idx] = r;
    float ss = r * r;
    #pragma unroll
    for (int o = 32; o > 0; o >>= 1) ss += __shfl_down(ss, o);
    __shared__ float ps[3];
    int wid = t >> 6;
    if ((t & 63) == 0) ps[wid] = ss;
    __syncthreads();
    float tot = ps[0] + ps[1] + ps[2];
    float inv = rsqrtf(tot / 192.f + 1e-5f);
    float v = r * inv * w[t];
    if (FINAL) ((float*)outp)[idx] = v;
    else       ((ushort_t*)outp)[idx] = f2b(v);
}

// ---------------- bf16 MFMA GEMM (dual-dir capable): C[M,N] = A[M,K] * W[N,K]^T ----------------
// OUTBF=0: fp32 out. OUTBF=1: bf16 out. dir = blockIdx.z selects pointer set.
template<int OUTBF>
__global__ __launch_bounds__(256) void gemm_bf16(const ushort_t* __restrict__ A0, const ushort_t* __restrict__ A1,
                                                 const ushort_t* __restrict__ W0, const ushort_t* __restrict__ W1,
                                                 void* __restrict__ C0, void* __restrict__ C1,
                                                 int M, int N, int K, int ldc) {
    __shared__ ushort_t As[128 * 40];
    __shared__ ushort_t Bs[64 * 40];
    int dir = blockIdx.z;
    const ushort_t* A = dir ? A1 : A0;
    const ushort_t* W = dir ? W1 : W0;
    void* C = dir ? C1 : C0;
    int tid = threadIdx.x;
    int m0 = blockIdx.y * 128, n0 = blockIdx.x * 64;
    int row = tid >> 2;
    int k8  = (tid & 3) * 8;
    int lane = tid & 63;
    int w = tid >> 6;
    int wr = w >> 1, wc = w & 1;
    int lr = lane & 15;
    int lk = (lane >> 4) * 8;
    f32x4 acc[4][2];
    #pragma unroll
    for (int i = 0; i < 4; i++)
        #pragma unroll
        for (int j = 0; j < 2; j++) acc[i][j] = (f32x4){0.f, 0.f, 0.f, 0.f};

    for (int k0 = 0; k0 < K; k0 += 32) {
        #pragma unroll
        for (int hhalf = 0; hhalf < 2; hhalf++) {
            int r = row + hhalf * 64;
            int m = m0 + r;
            bf16x8 v = {0,0,0,0,0,0,0,0};
            if (m < M) v = *(const bf16x8*)(A + (size_t)m * K + k0 + k8);
            *(bf16x8*)(&As[r * 40 + k8]) = v;
        }
        {
            int n = n0 + row;
            bf16x8 v = {0,0,0,0,0,0,0,0};
            if (n < N) v = *(const bf16x8*)(W + (size_t)n * K + k0 + k8);
            *(bf16x8*)(&Bs[row * 40 + k8]) = v;
        }
        __syncthreads();
        bf16x8 af[4], bfr[2];
        #pragma unroll
        for (int mi = 0; mi < 4; mi++)
            af[mi] = *(const bf16x8*)(&As[(wr * 64 + mi * 16 + lr) * 40 + lk]);
        #pragma unroll
        for (int ni = 0; ni < 2; ni++)
            bfr[ni] = *(const bf16x8*)(&Bs[(wc * 32 + ni * 16 + lr) * 40 + lk]);
        #pragma unroll
        for (int mi = 0; mi < 4; mi++)
            #pragma unroll
            for (int ni = 0; ni < 2; ni++)
                acc[mi][ni] = __builtin_amdgcn_mfma_f32_16x16x32_bf16(af[mi], bfr[ni], acc[mi][ni], 0, 0, 0);
        __syncthreads();
    }
    int rbase = (lane >> 4) * 4;
    #pragma unroll
    for (int mi = 0; mi < 4; mi++) {
        #pragma unroll
        for (int ni = 0; ni < 2; ni++) {
            #pragma unroll
            for (int r = 0; r < 4; r++) {
                int m = m0 + wr * 64 + mi * 16 + rbase + r;
                int n = n0 + wc * 32 + ni * 16 + lr;
                if (m < M && n < N) {
                    if (OUTBF) ((ushort_t*)C)[(size_t)m * ldc + n] = f2b(acc[mi][ni][r]);
                    else       ((float*)C)[(size_t)m * ldc + n] = acc[mi][ni][r];
                }
            }
        }
    }
}

// ---------------- out_proj GEMM with fused direction-combine on A ----------------
// A[m] = 0.5*(yf[b,l] + yr[b, 256-l]) where m = b*257+l, both bf16.
__global__ __launch_bounds__(256) void gemm_out(const ushort_t* __restrict__ yf, const ushort_t* __restrict__ yr,
                                                const ushort_t* __restrict__ W, float* __restrict__ C,
                                                int M, int N, int K, int ldc) {
    __shared__ ushort_t As[128 * 40];
    __shared__ ushort_t Bs[64 * 40];
    int tid = threadIdx.x;
    int m0 = blockIdx.y * 128, n0 = blockIdx.x * 64;
    int row = tid >> 2;
    int k8  = (tid & 3) * 8;
    int lane = tid & 63;
    int w = tid >> 6;
    int wr = w >> 1, wc = w & 1;
    int lr = lane & 15;
    int lk = (lane >> 4) * 8;
    // precompute per-thread A rows (forward and reversed)
    size_t rowf[2]; size_t rowr[2]; int mok[2];
    #pragma unroll
    for (int hhalf = 0; hhalf < 2; hhalf++) {
        int m = m0 + row + hhalf * 64;
        mok[hhalf] = (m < M);
        int b = m / SEQL;
        int l = m - b * SEQL;
        rowf[hhalf] = (size_t)m * 384;
        rowr[hhalf] = ((size_t)b * SEQL + (SEQL - 1 - l)) * 384;
    }
    f32x4 acc[4][2];
    #pragma unroll
    for (int i = 0; i < 4; i++)
        #pragma unroll
        for (int j = 0; j < 2; j++) acc[i][j] = (f32x4){0.f, 0.f, 0.f, 0.f};

    for (int k0 = 0; k0 < K; k0 += 32) {
        #pragma unroll
        for (int hhalf = 0; hhalf < 2; hhalf++) {
            int r = row + hhalf * 64;
            bf16x8 v = {0,0,0,0,0,0,0,0};
            if (mok[hhalf]) {
                bf16x8 vf = *(const bf16x8*)(yf + rowf[hhalf] + k0 + k8);
                bf16x8 vr = *(const bf16x8*)(yr + rowr[hhalf] + k0 + k8);
                #pragma unroll
                for (int j = 0; j < 8; j++) {
                    float a = b2f((ushort_t)vf[j]);
                    float bb = b2f((ushort_t)vr[j]);
                    v[j] = (short)f2b(0.5f * (a + bb));
                }
            }
            *(bf16x8*)(&As[r * 40 + k8]) = v;
        }
        {
            int n = n0 + row;
            bf16x8 v = {0,0,0,0,0,0,0,0};
            if (n < N) v = *(const bf16x8*)(W + (size_t)n * K + k0 + k8);
            *(bf16x8*)(&Bs[row * 40 + k8]) = v;
        }
        __syncthreads();
        bf16x8 af[4], bfr[2];
        #pragma unroll
        for (int mi = 0; mi < 4; mi++)
            af[mi] = *(const bf16x8*)(&As[(wr * 64 + mi * 16 + lr) * 40 + lk]);
        #pragma unroll
        for (int ni = 0; ni < 2; ni++)
            bfr[ni] = *(const bf16x8*)(&Bs[(wc * 32 + ni * 16 + lr) * 40 + lk]);
        #pragma unroll
        for (int mi = 0; mi < 4; mi++)
            #pragma unroll
            for (int ni = 0; ni < 2; ni++)
                acc[mi][ni] = __builtin_amdgcn_mfma_f32_16x16x32_bf16(af[mi], bfr[ni], acc[mi][ni], 0, 0, 0);
        __syncthreads();
    }
    int rbase = (lane >> 4) * 4;
    #pragma unroll
    for (int mi = 0; mi < 4; mi++) {
        #pragma unroll
        for (int ni = 0; ni < 2; ni++) {
            #pragma unroll
            for (int r = 0; r < 4; r++) {
                int m = m0 + wr * 64 + mi * 16 + rbase + r;
                int n = n0 + wc * 32 + ni * 16 + lr;
                if (m < M && n < N) C[(size_t)m * ldc + n] = acc[mi][ni][r];
            }
        }
    }
}

// ---------------- fp32 GEMM (dt_proj, dual-dir): C = softplus(A*W^T + bias) ----------------
__device__ __forceinline__ float softplus_f(float v) {
    return (v > 20.f) ? v : log1pf(expf(v));
}

__global__ __launch_bounds__(256) void gemm_dt(const float* __restrict__ A0, const float* __restrict__ A1, int lda,
                                               const float* __restrict__ W0, const float* __restrict__ W1, int ldb,
                                               float* __restrict__ C0, float* __restrict__ C1, int ldc,
                                               int M, int N, int K,
                                               const float* __restrict__ b0, const float* __restrict__ b1) {
    const int BM = 64, BN = 64, BK = 16;
    __shared__ float As[BK][BM + 4];
    __shared__ float Bs[BK][BN + 4];
    int dir = blockIdx.z;
    const float* A = dir ? A1 : A0;
    const float* Bw = dir ? W1 : W0;
    float* C = dir ? C1 : C0;
    const float* bias = dir ? b1 : b0;
    int m0 = blockIdx.y * BM, n0 = blockIdx.x * BN;
    int tid = threadIdx.x;
    int lr = tid >> 2, lk = (tid & 3) * 4;
    int tx = tid & 15, ty = tid >> 4;
    float acc[4][4] = {};
    for (int k0 = 0; k0 < K; k0 += BK) {
        {
            int m = m0 + lr, k = k0 + lk;
            float4 v = make_float4(0.f, 0.f, 0.f, 0.f);
            if (m < M && k < K) v = *(const float4*)(A + (size_t)m * lda + k);
            As[lk + 0][lr] = v.x; As[lk + 1][lr] = v.y; As[lk + 2][lr] = v.z; As[lk + 3][lr] = v.w;
            int n = n0 + lr;
            float4 wv = make_float4(0.f, 0.f, 0.f, 0.f);
            if (n < N && k < K) wv = *(const float4*)(Bw + (size_t)n * ldb + k);
            Bs[lk + 0][lr] = wv.x; Bs[lk + 1][lr] = wv.y; Bs[lk + 2][lr] = wv.z; Bs[lk + 3][lr] = wv.w;
        }
        __syncthreads();
        #pragma unroll
        for (int kk = 0; kk < BK; kk++) {
            float4 a  = *(const float4*)&As[kk][ty * 4];
            float4 bv = *(const float4*)&Bs[kk][tx * 4];
            float av[4] = {a.x, a.y, a.z, a.w};
            float bb[4] = {bv.x, bv.y, bv.z, bv.w};
            #pragma unroll
            for (int i2 = 0; i2 < 4; i2++)
                #pragma unroll
                for (int j = 0; j < 4; j++)
                    acc[i2][j] = fmaf(av[i2], bb[j], acc[i2][j]);
        }
        __syncthreads();
    }
    #pragma unroll
    for (int i2 = 0; i2 < 4; i2++) {
        int m = m0 + ty * 4 + i2;
        if (m >= M) continue;
        #pragma unroll
        for (int j = 0; j < 4; j++) {
            int n = n0 + tx * 4 + j;
            if (n >= N) continue;
            C[(size_t)m * ldc + n] = softplus_f(acc[i2][j] + bias[n]);
        }
    }
}

// ---------------- causal depthwise conv (k=4) + SiLU, both directions, bf16 in/out ----------------
__global__ __launch_bounds__(384) void conv_silu_k(const ushort_t* __restrict__ xz,
                                                   const float* __restrict__ cw, const float* __restrict__ cb,
                                                   const float* __restrict__ cwb, const float* __restrict__ cbb,
                                                   ushort_t* __restrict__ xcf, ushort_t* __restrict__ xcr) {
    int d = threadIdx.x;
    int l = blockIdx.x;
    int b = blockIdx.y;
    int dir = blockIdx.z;
    const float* w = dir ? cwb : cw;
    const float* bias = dir ? cbb : cb;
    float wr[4];
    {
        float4 wv = *(const float4*)(w + d * 4);
        wr[0] = wv.x; wr[1] = wv.y; wr[2] = wv.z; wr[3] = wv.w;
    }
    float acc = bias[d];
    #pragma unroll
    for (int k = 0; k < 4; k++) {
        int j = l - 3 + k;
        if (j < 0) continue;
        int lsrc = dir ? (SEQL - 1 - j) : j;
        float xv = b2f(xz[((size_t)b * SEQL + lsrc) * 768 + d]);
        acc = fmaf(wr[k], xv, acc);
    }
    float s = acc / (1.f + expf(-acc));
    ushort_t* out = dir ? xcr : xcf;
    out[((size_t)b * SEQL + l) * 384 + d] = f2b(s);
}

// ---------------- selective scan: 1 thread per (b,d,n) state ----------------
// block = 256 thr = 16 d-channels x 16 states; grid (24, B, 2). Writes y bf16.
__global__ __launch_bounds__(256) void scan_k(const float* __restrict__ dtf, const float* __restrict__ dtr,
                                              const ushort_t* __restrict__ xcf, const ushort_t* __restrict__ xcr,
                                              const float* __restrict__ dtbcf, const float* __restrict__ dtbcr,
                                              const ushort_t* __restrict__ xz,
                                              const float* __restrict__ Alf, const float* __restrict__ Alb,
                                              const float* __restrict__ Df, const float* __restrict__ Db,
                                              ushort_t* __restrict__ ybf, ushort_t* __restrict__ ybr) {
    __shared__ float bcs[SEQL * 32];   // 32.9 KB
    int t = threadIdx.x;
    int n = t & 15;
    int dl = t >> 4;                    // 0..15
    int d = blockIdx.x * 16 + dl;
    int b = blockIdx.y;
    int dir = blockIdx.z;
    const float* dtp = dir ? dtr : dtf;
    const ushort_t* xcp = dir ? xcr : xcf;
    const float* pbc = (dir ? dtbcr : dtbcf) + (size_t)b * SEQL * 44;
    ushort_t* yb = dir ? ybr : ybf;
    float A = -expf((dir ? Alb : Alf)[d * 16 + n]);
    float Dp = (dir ? Db : Df)[d];

    for (int i = t; i < SEQL * 8; i += 256) {
        int l = i >> 3, j = i & 7;
        *(float4*)(&bcs[l * 32 + j * 4]) = *(const float4*)(pbc + (size_t)l * 44 + 12 + j * 4);
    }
    __syncthreads();

    size_t rowbase = (size_t)b * SEQL;
    float h = 0.f;
    float dt_c = dtp[rowbase * 384 + d];
    float x_c  = b2f(xcp[rowbase * 384 + d]);
    float z_c  = b2f(xz[(dir ? (rowbase + SEQL - 1) : rowbase) * 768 + 384 + d]);
    for (int l = 0; l < SEQL; l++) {
        int ln = (l + 1 < SEQL) ? (l + 1) : l;
        float dt_n = dtp[(rowbase + ln) * 384 + d];
        float x_n  = b2f(xcp[(rowbase + ln) * 384 + d]);
        float z_n  = b2f(xz[(dir ? (rowbase + SEQL - 1 - ln) : (rowbase + ln)) * 768 + 384 + d]);

        float dA = __expf(dt_c * A);
        h = fmaf(h, dA, dt_c * x_c * bcs[l * 32 + n]);
        float p = h * bcs[l * 32 + 16 + n];
        p += __shfl_xor(p, 1);
        p += __shfl_xor(p, 2);
        p += __shfl_xor(p, 4);
        p += __shfl_xor(p, 8);
        if (n == 0) {
            float y = fmaf(Dp, x_c, p);
            float sz = z_c / (1.f + __expf(-z_c));
            yb[(rowbase + l) * 384 + d] = f2b(y * sz);
        }
        dt_c = dt_n; x_c = x_n; z_c = z_n;
    }
}

extern "C" void kernel_launch(void* const* d_in, const int* in_sizes, int n_in,
                              void* d_out, int out_size, void* d_ws, size_t ws_size,
                              hipStream_t stream) {
    const float* x         = (const float*)d_in[0];
    const float* patch_w   = (const float*)d_in[1];
    const float* patch_b   = (const float*)d_in[2];
    const float* cls_token = (const float*)d_in[3];
    const float* pos_embed = (const float*)d_in[4];
    const float* norm_w    = (const float*)d_in[5];
    const float* in_proj_w = (const float*)d_in[6];
    const float* conv_w    = (const float*)d_in[7];
    const float* conv_b    = (const float*)d_in[8];
    const float* xproj_w   = (const float*)d_in[9];
    const float* dtproj_w  = (const float*)d_in[10];
    const float* dt_bias   = (const float*)d_in[11];
    const float* A_log     = (const float*)d_in[12];
    const float* Dskip     = (const float*)d_in[13];
    const float* conv_w_b  = (const float*)d_in[14];
    const float* conv_b_b  = (const float*)d_in[15];
    const float* xproj_w_b = (const float*)d_in[16];
    const float* dtproj_w_b= (const float*)d_in[17];
    const float* dt_bias_b = (const float*)d_in[18];
    const float* A_log_b   = (const float*)d_in[19];
    const float* Dskip_b   = (const float*)d_in[20];
    const float* out_proj_w= (const float*)d_in[21];
    const float* norm_f_w  = (const float*)d_in[22];

    float* ws = (float*)d_ws;
    size_t off = 0;
    float* res   = ws + off; off += (size_t)NTOK * 192;
    float* hbuf  = ws + off; off += (size_t)NTOK * 192;
    ushort_t* xzb = (ushort_t*)(ws + off); off += (size_t)NTOK * 384;   // NTOK*768 ushorts; also Apatch
    ushort_t* hnb = (ushort_t*)(ws + off); off += (size_t)NTOK * 96;
    ushort_t* xcfb = (ushort_t*)(ws + off); off += (size_t)NTOK * 192;
    ushort_t* xcrb = (ushort_t*)(ws + off); off += (size_t)NTOK * 192;
    float* dtf   = ws + off; off += (size_t)NTOK * 384;                 // also Ppatch fp32
    float* dtr   = ws + off; off += (size_t)NTOK * 384;
    float* dtbcf = ws + off; off += (size_t)NTOK * 44;
    float* dtbcr = ws + off; off += (size_t)NTOK * 44;
    ushort_t* ybf = (ushort_t*)(ws + off); off += (size_t)NTOK * 192;
    ushort_t* ybr = (ushort_t*)(ws + off); off += (size_t)NTOK * 192;
    ushort_t* wb = (ushort_t*)(ws + off);
    ushort_t* winb   = wb;
    ushort_t* woutb  = winb  + 3538944;
    ushort_t* xpfb   = woutb + 1769472;
    ushort_t* xprb   = xpfb  + 405504;
    ushort_t* patchwb= xprb  + 405504;

    ushort_t* Apatch = xzb;
    float* Ppatch = dtf;

    convert_k<<<(3538944/4 + 255)/256, 256, 0, stream>>>(in_proj_w, winb, 3538944);
    convert_k<<<(1769472/4 + 255)/256, 256, 0, stream>>>(out_proj_w, woutb, 1769472);
    convert_k<<<(405504/4 + 255)/256, 256, 0, stream>>>(xproj_w, xpfb, 405504);
    convert_k<<<(405504/4 + 255)/256, 256, 0, stream>>>(xproj_w_b, xprb, 405504);
    convert_k<<<(147456/4 + 255)/256, 256, 0, stream>>>(patch_w, patchwb, 147456);

    hipMemsetAsync(res, 0, (size_t)NTOK * 192 * sizeof(float), stream);

    rearrange_k<<<6144, 256, 0, stream>>>(x, Apatch);
    gemm_bf16<0><<<dim3(3, 64, 1), 256, 0, stream>>>(Apatch, Apatch, patchwb, patchwb,
                                                     Ppatch, Ppatch, 8192, 192, 768, 192);
    assemble_k<<<dim3(SEQL, BATCH), 192, 0, stream>>>(Ppatch, patch_b, cls_token, pos_embed, hbuf);

    for (int i = 0; i < DEPTH; i++) {
        const float* nw   = norm_w + i * 192;
        const float* cwf  = conv_w + (size_t)i * 384 * 4;
        const float* cbf  = conv_b + (size_t)i * 384;
        const float* cwr  = conv_w_b + (size_t)i * 384 * 4;
        const float* cbr  = conv_b_b + (size_t)i * 384;
        const float* dpf  = dtproj_w + (size_t)i * 384 * 12;
        const float* dpr  = dtproj_w_b + (size_t)i * 384 * 12;
        const float* dbf  = dt_bias + (size_t)i * 384;
        const float* dbr  = dt_bias_b + (size_t)i * 384;
        const float* alf  = A_log + (size_t)i * 384 * 16;
        const float* alr  = A_log_b + (size_t)i * 384 * 16;
        const float* dsf  = Dskip + (size_t)i * 384;
        const float* dsr  = Dskip_b + (size_t)i * 384;

        addnorm_k<0><<<NTOK, 192, 0, stream>>>(res, hbuf, nw, hnb);
        gemm_bf16<1><<<dim3(12, 65, 1), 256, 0, stream>>>(hnb, hnb,
                                                          winb + (size_t)i * 768 * 192, winb + (size_t)i * 768 * 192,
                                                          xzb, xzb, NTOK, 768, 192, 768);
        conv_silu_k<<<dim3(SEQL, BATCH, 2), 384, 0, stream>>>(xzb, cwf, cbf, cwr, cbr, xcfb, xcrb);
        gemm_bf16<0><<<dim3(1, 65, 2), 256, 0, stream>>>(xcfb, xcrb,
                                                         xpfb + (size_t)i * 44 * 384, xprb + (size_t)i * 44 * 384,
                                                         dtbcf, dtbcr, NTOK, 44, 384, 44);
        gemm_dt<<<dim3(6, 129, 2), 256, 0, stream>>>(dtbcf, dtbcr, 44, dpf, dpr, 12,
                                                     dtf, dtr, 384, NTOK, 384, 12, dbf, dbr);
        scan_k<<<dim3(24, BATCH, 2), 256, 0, stream>>>(dtf, dtr, xcfb, xcrb, dtbcf, dtbcr, xzb,
                                                       alf, alr, dsf, dsr, ybf, ybr);
        gemm_out<<<dim3(3, 65, 1), 256, 0, stream>>>(ybf, ybr, woutb + (size_t)i * 192 * 384, hbuf,
                                                     NTOK, 192, 384, 192);
    }

    addnorm_k<1><<<NTOK, 192, 0, stream>>>(res, hbuf, norm_f_w, (float*)d_out);
}

// Round 4
// 4295.222 us; speedup vs baseline: 1.8502x; 1.8502x over previous
//
#include <hip/hip_runtime.h>
#include <hip/hip_bf16.h>
#include <math.h>

#define D_MODEL 192
#define D_INNER 384
#define D_STATE 16
#define DT_RANK 12
#define DEPTH   24
#define SEQL    257
#define BATCH   32
#define NTOK    (BATCH*SEQL)   // 8224
#define NC      8              // sequence chunks for the scan
#define CL      33             // chunk length (8*33 = 264 >= 257)

typedef unsigned short ushort_t;
using bf16x8 = __attribute__((ext_vector_type(8))) short;
using f32x4  = __attribute__((ext_vector_type(4))) float;

__device__ __forceinline__ ushort_t f2b(float f) {
    __hip_bfloat16 h = __float2bfloat16(f);
    return reinterpret_cast<ushort_t&>(h);
}
__device__ __forceinline__ float b2f(ushort_t u) {
    __hip_bfloat16 h;
    reinterpret_cast<ushort_t&>(h) = u;
    return __bfloat162float(h);
}

// ---------------- fp32 -> bf16 conversion ----------------
__global__ __launch_bounds__(256) void convert_k(const float* __restrict__ in, ushort_t* __restrict__ out, int n) {
    int i = (blockIdx.x * 256 + threadIdx.x) * 4;
    if (i + 3 < n) {
        float4 v = *(const float4*)(in + i);
        ushort4 o;
        o.x = f2b(v.x); o.y = f2b(v.y); o.z = f2b(v.z); o.w = f2b(v.w);
        *(ushort4*)(out + i) = o;
    } else {
        for (int j = i; j < n; j++) out[j] = f2b(in[j]);
    }
}

// ---------------- patch rearrange: x (B,3,256,256) -> Apatch bf16 (B*256, 768) ----------------
__global__ __launch_bounds__(256) void rearrange_k(const float* __restrict__ x, ushort_t* __restrict__ Ap) {
    size_t i = (size_t)blockIdx.x * 256 + threadIdx.x;
    const size_t total = (size_t)8192 * 768 / 4;
    if (i >= total) return;
    size_t o = i * 4;
    int bt  = (int)(o / 768);
    int rem = (int)(o % 768);
    int c  = rem >> 8;
    int r2 = rem & 255;
    int pi = r2 >> 4;
    int pj = r2 & 15;
    int b = bt >> 8;
    int t = bt & 255;
    int ph = t >> 4, pw = t & 15;
    size_t src = (((size_t)(b * 3 + c) * 256) + (size_t)(ph * 16 + pi)) * 256 + (pw * 16 + pj);
    float4 v = *(const float4*)(x + src);
    ushort4 ov;
    ov.x = f2b(v.x); ov.y = f2b(v.y); ov.z = f2b(v.z); ov.w = f2b(v.w);
    *(ushort4*)(Ap + o) = ov;
}

// ---------------- assemble: insert cls token, add patch bias + pos embed ----------------
__global__ __launch_bounds__(192) void assemble_k(const float* __restrict__ P, const float* __restrict__ pb,
                                                  const float* __restrict__ cls, const float* __restrict__ pos,
                                                  float* __restrict__ hb) {
    int o = threadIdx.x;
    int l = blockIdx.x;
    int b = blockIdx.y;
    float v;
    if (l == 128) {
        v = cls[o];
    } else {
        int t = (l < 128) ? l : l - 1;
        v = P[((size_t)b * 256 + t) * 192 + o] + pb[o];
    }
    hb[((size_t)b * SEQL + l) * 192 + o] = v + pos[l * 192 + o];
}

// ---------------- fused add + RMSNorm ----------------
template<int FINAL>
__global__ __launch_bounds__(192) void addnorm_k(float* res, const float* __restrict__ h,
                                                 const float* __restrict__ w, void* __restrict__ outp) {
    int row = blockIdx.x;
    int t = threadIdx.x;
    size_t idx = (size_t)row * 192 + t;
    float r = res[idx] + h[idx];
    if (!FINAL) res[idx] = r;
    float ss = r * r;
    #pragma unroll
    for (int o = 32; o > 0; o >>= 1) ss += __shfl_down(ss, o);
    __shared__ float ps[3];
    int wid = t >> 6;
    if ((t & 63) == 0) ps[wid] = ss;
    __syncthreads();
    float tot = ps[0] + ps[1] + ps[2];
    float inv = rsqrtf(tot / 192.f + 1e-5f);
    float v = r * inv * w[t];
    if (FINAL) ((float*)outp)[idx] = v;
    else       ((ushort_t*)outp)[idx] = f2b(v);
}

// ---------------- bf16 MFMA GEMM (dual-dir capable): C[M,N] = A[M,K] * W[N,K]^T ----------------
template<int OUTBF>
__global__ __launch_bounds__(256) void gemm_bf16(const ushort_t* __restrict__ A0, const ushort_t* __restrict__ A1,
                                                 const ushort_t* __restrict__ W0, const ushort_t* __restrict__ W1,
                                                 void* __restrict__ C0, void* __restrict__ C1,
                                                 int M, int N, int K, int ldc) {
    __shared__ ushort_t As[128 * 40];
    __shared__ ushort_t Bs[64 * 40];
    int dir = blockIdx.z;
    const ushort_t* A = dir ? A1 : A0;
    const ushort_t* W = dir ? W1 : W0;
    void* C = dir ? C1 : C0;
    int tid = threadIdx.x;
    int m0 = blockIdx.y * 128, n0 = blockIdx.x * 64;
    int row = tid >> 2;
    int k8  = (tid & 3) * 8;
    int lane = tid & 63;
    int w = tid >> 6;
    int wr = w >> 1, wc = w & 1;
    int lr = lane & 15;
    int lk = (lane >> 4) * 8;
    f32x4 acc[4][2];
    #pragma unroll
    for (int i = 0; i < 4; i++)
        #pragma unroll
        for (int j = 0; j < 2; j++) acc[i][j] = (f32x4){0.f, 0.f, 0.f, 0.f};

    for (int k0 = 0; k0 < K; k0 += 32) {
        #pragma unroll
        for (int hhalf = 0; hhalf < 2; hhalf++) {
            int r = row + hhalf * 64;
            int m = m0 + r;
            bf16x8 v = {0,0,0,0,0,0,0,0};
            if (m < M) v = *(const bf16x8*)(A + (size_t)m * K + k0 + k8);
            *(bf16x8*)(&As[r * 40 + k8]) = v;
        }
        {
            int n = n0 + row;
            bf16x8 v = {0,0,0,0,0,0,0,0};
            if (n < N) v = *(const bf16x8*)(W + (size_t)n * K + k0 + k8);
            *(bf16x8*)(&Bs[row * 40 + k8]) = v;
        }
        __syncthreads();
        bf16x8 af[4], bfr[2];
        #pragma unroll
        for (int mi = 0; mi < 4; mi++)
            af[mi] = *(const bf16x8*)(&As[(wr * 64 + mi * 16 + lr) * 40 + lk]);
        #pragma unroll
        for (int ni = 0; ni < 2; ni++)
            bfr[ni] = *(const bf16x8*)(&Bs[(wc * 32 + ni * 16 + lr) * 40 + lk]);
        #pragma unroll
        for (int mi = 0; mi < 4; mi++)
            #pragma unroll
            for (int ni = 0; ni < 2; ni++)
                acc[mi][ni] = __builtin_amdgcn_mfma_f32_16x16x32_bf16(af[mi], bfr[ni], acc[mi][ni], 0, 0, 0);
        __syncthreads();
    }
    int rbase = (lane >> 4) * 4;
    #pragma unroll
    for (int mi = 0; mi < 4; mi++) {
        #pragma unroll
        for (int ni = 0; ni < 2; ni++) {
            #pragma unroll
            for (int r = 0; r < 4; r++) {
                int m = m0 + wr * 64 + mi * 16 + rbase + r;
                int n = n0 + wc * 32 + ni * 16 + lr;
                if (m < M && n < N) {
                    if (OUTBF) ((ushort_t*)C)[(size_t)m * ldc + n] = f2b(acc[mi][ni][r]);
                    else       ((float*)C)[(size_t)m * ldc + n] = acc[mi][ni][r];
                }
            }
        }
    }
}

// ---------------- out_proj GEMM with fused direction-combine on A ----------------
__global__ __launch_bounds__(256) void gemm_out(const ushort_t* __restrict__ yf, const ushort_t* __restrict__ yr,
                                                const ushort_t* __restrict__ W, float* __restrict__ C,
                                                int M, int N, int K, int ldc) {
    __shared__ ushort_t As[128 * 40];
    __shared__ ushort_t Bs[64 * 40];
    int tid = threadIdx.x;
    int m0 = blockIdx.y * 128, n0 = blockIdx.x * 64;
    int row = tid >> 2;
    int k8  = (tid & 3) * 8;
    int lane = tid & 63;
    int w = tid >> 6;
    int wr = w >> 1, wc = w & 1;
    int lr = lane & 15;
    int lk = (lane >> 4) * 8;
    size_t rowf[2]; size_t rowr[2]; int mok[2];
    #pragma unroll
    for (int hhalf = 0; hhalf < 2; hhalf++) {
        int m = m0 + row + hhalf * 64;
        mok[hhalf] = (m < M);
        int b = m / SEQL;
        int l = m - b * SEQL;
        rowf[hhalf] = (size_t)m * 384;
        rowr[hhalf] = ((size_t)b * SEQL + (SEQL - 1 - l)) * 384;
    }
    f32x4 acc[4][2];
    #pragma unroll
    for (int i = 0; i < 4; i++)
        #pragma unroll
        for (int j = 0; j < 2; j++) acc[i][j] = (f32x4){0.f, 0.f, 0.f, 0.f};

    for (int k0 = 0; k0 < K; k0 += 32) {
        #pragma unroll
        for (int hhalf = 0; hhalf < 2; hhalf++) {
            int r = row + hhalf * 64;
            bf16x8 v = {0,0,0,0,0,0,0,0};
            if (mok[hhalf]) {
                bf16x8 vf = *(const bf16x8*)(yf + rowf[hhalf] + k0 + k8);
                bf16x8 vr = *(const bf16x8*)(yr + rowr[hhalf] + k0 + k8);
                #pragma unroll
                for (int j = 0; j < 8; j++) {
                    float a = b2f((ushort_t)vf[j]);
                    float bb = b2f((ushort_t)vr[j]);
                    v[j] = (short)f2b(0.5f * (a + bb));
                }
            }
            *(bf16x8*)(&As[r * 40 + k8]) = v;
        }
        {
            int n = n0 + row;
            bf16x8 v = {0,0,0,0,0,0,0,0};
            if (n < N) v = *(const bf16x8*)(W + (size_t)n * K + k0 + k8);
            *(bf16x8*)(&Bs[row * 40 + k8]) = v;
        }
        __syncthreads();
        bf16x8 af[4], bfr[2];
        #pragma unroll
        for (int mi = 0; mi < 4; mi++)
            af[mi] = *(const bf16x8*)(&As[(wr * 64 + mi * 16 + lr) * 40 + lk]);
        #pragma unroll
        for (int ni = 0; ni < 2; ni++)
            bfr[ni] = *(const bf16x8*)(&Bs[(wc * 32 + ni * 16 + lr) * 40 + lk]);
        #pragma unroll
        for (int mi = 0; mi < 4; mi++)
            #pragma unroll
            for (int ni = 0; ni < 2; ni++)
                acc[mi][ni] = __builtin_amdgcn_mfma_f32_16x16x32_bf16(af[mi], bfr[ni], acc[mi][ni], 0, 0, 0);
        __syncthreads();
    }
    int rbase = (lane >> 4) * 4;
    #pragma unroll
    for (int mi = 0; mi < 4; mi++) {
        #pragma unroll
        for (int ni = 0; ni < 2; ni++) {
            #pragma unroll
            for (int r = 0; r < 4; r++) {
                int m = m0 + wr * 64 + mi * 16 + rbase + r;
                int n = n0 + wc * 32 + ni * 16 + lr;
                if (m < M && n < N) C[(size_t)m * ldc + n] = acc[mi][ni][r];
            }
        }
    }
}

// ---------------- fp32 GEMM (dt_proj, dual-dir): C = softplus(A*W^T + bias) ----------------
__device__ __forceinline__ float softplus_f(float v) {
    return (v > 20.f) ? v : log1pf(expf(v));
}

__global__ __launch_bounds__(256) void gemm_dt(const float* __restrict__ A0, const float* __restrict__ A1, int lda,
                                               const float* __restrict__ W0, const float* __restrict__ W1, int ldb,
                                               float* __restrict__ C0, float* __restrict__ C1, int ldc,
                                               int M, int N, int K,
                                               const float* __restrict__ b0, const float* __restrict__ b1) {
    const int BM = 64, BN = 64, BK = 16;
    __shared__ float As[BK][BM + 4];
    __shared__ float Bs[BK][BN + 4];
    int dir = blockIdx.z;
    const float* A = dir ? A1 : A0;
    const float* Bw = dir ? W1 : W0;
    float* C = dir ? C1 : C0;
    const float* bias = dir ? b1 : b0;
    int m0 = blockIdx.y * BM, n0 = blockIdx.x * BN;
    int tid = threadIdx.x;
    int lr = tid >> 2, lk = (tid & 3) * 4;
    int tx = tid & 15, ty = tid >> 4;
    float acc[4][4] = {};
    for (int k0 = 0; k0 < K; k0 += BK) {
        {
            int m = m0 + lr, k = k0 + lk;
            float4 v = make_float4(0.f, 0.f, 0.f, 0.f);
            if (m < M && k < K) v = *(const float4*)(A + (size_t)m * lda + k);
            As[lk + 0][lr] = v.x; As[lk + 1][lr] = v.y; As[lk + 2][lr] = v.z; As[lk + 3][lr] = v.w;
            int n = n0 + lr;
            float4 wv = make_float4(0.f, 0.f, 0.f, 0.f);
            if (n < N && k < K) wv = *(const float4*)(Bw + (size_t)n * ldb + k);
            Bs[lk + 0][lr] = wv.x; Bs[lk + 1][lr] = wv.y; Bs[lk + 2][lr] = wv.z; Bs[lk + 3][lr] = wv.w;
        }
        __syncthreads();
        #pragma unroll
        for (int kk = 0; kk < BK; kk++) {
            float4 a  = *(const float4*)&As[kk][ty * 4];
            float4 bv = *(const float4*)&Bs[kk][tx * 4];
            float av[4] = {a.x, a.y, a.z, a.w};
            float bb[4] = {bv.x, bv.y, bv.z, bv.w};
            #pragma unroll
            for (int i2 = 0; i2 < 4; i2++)
                #pragma unroll
                for (int j = 0; j < 4; j++)
                    acc[i2][j] = fmaf(av[i2], bb[j], acc[i2][j]);
        }
        __syncthreads();
    }
    #pragma unroll
    for (int i2 = 0; i2 < 4; i2++) {
        int m = m0 + ty * 4 + i2;
        if (m >= M) continue;
        #pragma unroll
        for (int j = 0; j < 4; j++) {
            int n = n0 + tx * 4 + j;
            if (n >= N) continue;
            C[(size_t)m * ldc + n] = softplus_f(acc[i2][j] + bias[n]);
        }
    }
}

// ---------------- causal depthwise conv (k=4) + SiLU, both directions, bf16 in/out ----------------
__global__ __launch_bounds__(384) void conv_silu_k(const ushort_t* __restrict__ xz,
                                                   const float* __restrict__ cw, const float* __restrict__ cb,
                                                   const float* __restrict__ cwb, const float* __restrict__ cbb,
                                                   ushort_t* __restrict__ xcf, ushort_t* __restrict__ xcr) {
    int d = threadIdx.x;
    int l = blockIdx.x;
    int b = blockIdx.y;
    int dir = blockIdx.z;
    const float* w = dir ? cwb : cw;
    const float* bias = dir ? cbb : cb;
    float wr[4];
    {
        float4 wv = *(const float4*)(w + d * 4);
        wr[0] = wv.x; wr[1] = wv.y; wr[2] = wv.z; wr[3] = wv.w;
    }
    float acc = bias[d];
    #pragma unroll
    for (int k = 0; k < 4; k++) {
        int j = l - 3 + k;
        if (j < 0) continue;
        int lsrc = dir ? (SEQL - 1 - j) : j;
        float xv = b2f(xz[((size_t)b * SEQL + lsrc) * 768 + d]);
        acc = fmaf(wr[k], xv, acc);
    }
    float s = acc / (1.f + expf(-acc));
    ushort_t* out = dir ? xcr : xcf;
    out[((size_t)b * SEQL + l) * 384 + d] = f2b(s);
}

// ============ chunked selective scan ============
// pass 1: per chunk, from h=0 compute S[16] (chunk-local scan) and sum(dt).
// blocks: (6 dchunks x NC chunks, B, 2); 64 threads, d = dchunk*64+tid.
__global__ __launch_bounds__(64) void scan_p1(const float* __restrict__ dtf, const float* __restrict__ dtr,
                                              const ushort_t* __restrict__ xcf, const ushort_t* __restrict__ xcr,
                                              const float* __restrict__ dtbcf, const float* __restrict__ dtbcr,
                                              const float* __restrict__ Alf, const float* __restrict__ Alb,
                                              float* __restrict__ Sbuf, float* __restrict__ sumdt) {
    __shared__ float bs[CL * 16];
    int tid = threadIdx.x;
    int dchunk = blockIdx.x % 6, c = blockIdx.x / 6;
    int d = dchunk * 64 + tid;
    int b = blockIdx.y, dir = blockIdx.z;
    int bd = b * 2 + dir;
    const float* dtp = dir ? dtr : dtf;
    const ushort_t* xcp = dir ? xcr : xcf;
    const float* pbc = (dir ? dtbcr : dtbcf) + (size_t)b * SEQL * 44;
    int lstart = c * CL;
    int lend = (lstart + CL < SEQL) ? (lstart + CL) : SEQL;
    int clen = lend - lstart;

    for (int i = tid; i < clen * 4; i += 64) {
        int l = i >> 2, j = i & 3;
        *(float4*)(&bs[l * 16 + j * 4]) = *(const float4*)(pbc + (size_t)(lstart + l) * 44 + 12 + j * 4);
    }
    __syncthreads();

    const float* alog = (dir ? Alb : Alf) + d * 16;
    float A[16];
    #pragma unroll
    for (int n = 0; n < 16; n++) A[n] = -__expf(alog[n]);
    float S[16];
    #pragma unroll
    for (int n = 0; n < 16; n++) S[n] = 0.f;
    float ssum = 0.f;

    size_t rowbase = (size_t)b * SEQL + lstart;
    float dt_c = dtp[rowbase * 384 + d];
    float x_c  = b2f(xcp[rowbase * 384 + d]);
    for (int l = 0; l < clen; l++) {
        int ln = (l + 1 < clen) ? (l + 1) : l;
        float dt_n = dtp[(rowbase + ln) * 384 + d];
        float x_n  = b2f(xcp[(rowbase + ln) * 384 + d]);
        float dtx = dt_c * x_c;
        ssum += dt_c;
        #pragma unroll
        for (int n = 0; n < 16; n++)
            S[n] = fmaf(S[n], __expf(dt_c * A[n]), dtx * bs[l * 16 + n]);
        dt_c = dt_n; x_c = x_n;
    }
    float* sp = Sbuf + ((size_t)bd * NC + c) * 6144 + d * 16;
    #pragma unroll
    for (int j = 0; j < 4; j++)
        *(float4*)(sp + j * 4) = make_float4(S[j*4], S[j*4+1], S[j*4+2], S[j*4+3]);
    sumdt[((size_t)bd * NC + c) * 384 + d] = ssum;
}

// pass 2: prefix over chunks; converts Sbuf in place into h_in per chunk.
// 1 thread per (b,dir,d,n) = 393216 threads.
__global__ __launch_bounds__(256) void scan_mid(float* __restrict__ Sbuf, const float* __restrict__ sumdt,
                                                const float* __restrict__ Alf, const float* __restrict__ Alb) {
    int gid = blockIdx.x * 256 + threadIdx.x;
    int n = gid & 15;
    int rest = gid >> 4;
    int d = rest % 384;
    int bd = rest / 384;            // b*2 + dir
    int dir = bd & 1;
    float A = -__expf((dir ? Alb : Alf)[d * 16 + n]);
    float h = 0.f;
    #pragma unroll
    for (int c = 0; c < NC; c++) {
        size_t si = ((size_t)bd * NC + c) * 6144 + d * 16 + n;
        float S = Sbuf[si];
        float sd = sumdt[((size_t)bd * NC + c) * 384 + d];
        Sbuf[si] = h;                       // h_in for this chunk
        h = fmaf(h, __expf(A * sd), S);
    }
}

// pass 3: re-scan each chunk from h_in, emit y = (scan + D*x) * silu(z), bf16.
__global__ __launch_bounds__(64) void scan_p3(const float* __restrict__ dtf, const float* __restrict__ dtr,
                                              const ushort_t* __restrict__ xcf, const ushort_t* __restrict__ xcr,
                                              const float* __restrict__ dtbcf, const float* __restrict__ dtbcr,
                                              const ushort_t* __restrict__ xz,
                                              const float* __restrict__ Alf, const float* __restrict__ Alb,
                                              const float* __restrict__ Df, const float* __restrict__ Db,
                                              const float* __restrict__ hinbuf,
                                              ushort_t* __restrict__ ybf, ushort_t* __restrict__ ybr) {
    __shared__ float bcs[CL * 32];
    int tid = threadIdx.x;
    int dchunk = blockIdx.x % 6, c = blockIdx.x / 6;
    int d = dchunk * 64 + tid;
    int b = blockIdx.y, dir = blockIdx.z;
    int bd = b * 2 + dir;
    const float* dtp = dir ? dtr : dtf;
    const ushort_t* xcp = dir ? xcr : xcf;
    const float* pbc = (dir ? dtbcr : dtbcf) + (size_t)b * SEQL * 44;
    ushort_t* yb = dir ? ybr : ybf;
    int lstart = c * CL;
    int lend = (lstart + CL < SEQL) ? (lstart + CL) : SEQL;
    int clen = lend - lstart;

    for (int i = tid; i < clen * 8; i += 64) {
        int l = i >> 3, j = i & 7;
        *(float4*)(&bcs[l * 32 + j * 4]) = *(const float4*)(pbc + (size_t)(lstart + l) * 44 + 12 + j * 4);
    }
    __syncthreads();

    const float* alog = (dir ? Alb : Alf) + d * 16;
    float A[16], h[16];
    #pragma unroll
    for (int n = 0; n < 16; n++) A[n] = -__expf(alog[n]);
    {
        const float4* hp = (const float4*)(hinbuf + ((size_t)bd * NC + c) * 6144 + d * 16);
        #pragma unroll
        for (int j = 0; j < 4; j++) {
            float4 hv = hp[j];
            h[j*4] = hv.x; h[j*4+1] = hv.y; h[j*4+2] = hv.z; h[j*4+3] = hv.w;
        }
    }
    float Dp = (dir ? Db : Df)[d];

    size_t rowbase = (size_t)b * SEQL + lstart;
    size_t seqbase = (size_t)b * SEQL;
    float dt_c = dtp[rowbase * 384 + d];
    float x_c  = b2f(xcp[rowbase * 384 + d]);
    float z_c  = b2f(xz[(dir ? (seqbase + SEQL - 1 - lstart) : rowbase) * 768 + 384 + d]);
    for (int l = 0; l < clen; l++) {
        int ln = (l + 1 < clen) ? (l + 1) : l;
        float dt_n = dtp[(rowbase + ln) * 384 + d];
        float x_n  = b2f(xcp[(rowbase + ln) * 384 + d]);
        float z_n  = b2f(xz[(dir ? (seqbase + SEQL - 1 - (lstart + ln)) : (rowbase + ln)) * 768 + 384 + d]);

        float dtx = dt_c * x_c;
        float y = 0.f;
        #pragma unroll
        for (int n = 0; n < 16; n++) {
            h[n] = fmaf(h[n], __expf(dt_c * A[n]), dtx * bcs[l * 32 + n]);
            y = fmaf(h[n], bcs[l * 32 + 16 + n], y);
        }
        y = fmaf(Dp, x_c, y);
        float sz = z_c / (1.f + __expf(-z_c));
        yb[(rowbase + l) * 384 + d] = f2b(y * sz);
        dt_c = dt_n; x_c = x_n; z_c = z_n;
    }
}

extern "C" void kernel_launch(void* const* d_in, const int* in_sizes, int n_in,
                              void* d_out, int out_size, void* d_ws, size_t ws_size,
                              hipStream_t stream) {
    const float* x         = (const float*)d_in[0];
    const float* patch_w   = (const float*)d_in[1];
    const float* patch_b   = (const float*)d_in[2];
    const float* cls_token = (const float*)d_in[3];
    const float* pos_embed = (const float*)d_in[4];
    const float* norm_w    = (const float*)d_in[5];
    const float* in_proj_w = (const float*)d_in[6];
    const float* conv_w    = (const float*)d_in[7];
    const float* conv_b    = (const float*)d_in[8];
    const float* xproj_w   = (const float*)d_in[9];
    const float* dtproj_w  = (const float*)d_in[10];
    const float* dt_bias   = (const float*)d_in[11];
    const float* A_log     = (const float*)d_in[12];
    const float* Dskip     = (const float*)d_in[13];
    const float* conv_w_b  = (const float*)d_in[14];
    const float* conv_b_b  = (const float*)d_in[15];
    const float* xproj_w_b = (const float*)d_in[16];
    const float* dtproj_w_b= (const float*)d_in[17];
    const float* dt_bias_b = (const float*)d_in[18];
    const float* A_log_b   = (const float*)d_in[19];
    const float* Dskip_b   = (const float*)d_in[20];
    const float* out_proj_w= (const float*)d_in[21];
    const float* norm_f_w  = (const float*)d_in[22];

    float* ws = (float*)d_ws;
    size_t off = 0;
    float* res   = ws + off; off += (size_t)NTOK * 192;
    float* hbuf  = ws + off; off += (size_t)NTOK * 192;
    ushort_t* xzb = (ushort_t*)(ws + off); off += (size_t)NTOK * 384;   // NTOK*768 ushorts; also Apatch
    ushort_t* hnb = (ushort_t*)(ws + off); off += (size_t)NTOK * 96;
    ushort_t* xcfb = (ushort_t*)(ws + off); off += (size_t)NTOK * 192;
    ushort_t* xcrb = (ushort_t*)(ws + off); off += (size_t)NTOK * 192;
    float* dtf   = ws + off; off += (size_t)NTOK * 384;                 // also Ppatch fp32
    float* dtr   = ws + off; off += (size_t)NTOK * 384;
    float* dtbcf = ws + off; off += (size_t)NTOK * 44;
    float* dtbcr = ws + off; off += (size_t)NTOK * 44;
    ushort_t* ybf = (ushort_t*)(ws + off); off += (size_t)NTOK * 192;
    ushort_t* ybr = (ushort_t*)(ws + off); off += (size_t)NTOK * 192;
    float* Sbuf  = ws + off; off += (size_t)BATCH * 2 * NC * 6144;      // 3.15M floats (S -> h_in in place)
    float* sumdt = ws + off; off += (size_t)BATCH * 2 * NC * 384;       // 0.20M floats
    ushort_t* wb = (ushort_t*)(ws + off);
    ushort_t* winb   = wb;
    ushort_t* woutb  = winb  + 3538944;
    ushort_t* xpfb   = woutb + 1769472;
    ushort_t* xprb   = xpfb  + 405504;
    ushort_t* patchwb= xprb  + 405504;

    ushort_t* Apatch = xzb;
    float* Ppatch = dtf;

    convert_k<<<(3538944/4 + 255)/256, 256, 0, stream>>>(in_proj_w, winb, 3538944);
    convert_k<<<(1769472/4 + 255)/256, 256, 0, stream>>>(out_proj_w, woutb, 1769472);
    convert_k<<<(405504/4 + 255)/256, 256, 0, stream>>>(xproj_w, xpfb, 405504);
    convert_k<<<(405504/4 + 255)/256, 256, 0, stream>>>(xproj_w_b, xprb, 405504);
    convert_k<<<(147456/4 + 255)/256, 256, 0, stream>>>(patch_w, patchwb, 147456);

    hipMemsetAsync(res, 0, (size_t)NTOK * 192 * sizeof(float), stream);

    rearrange_k<<<6144, 256, 0, stream>>>(x, Apatch);
    gemm_bf16<0><<<dim3(3, 64, 1), 256, 0, stream>>>(Apatch, Apatch, patchwb, patchwb,
                                                     Ppatch, Ppatch, 8192, 192, 768, 192);
    assemble_k<<<dim3(SEQL, BATCH), 192, 0, stream>>>(Ppatch, patch_b, cls_token, pos_embed, hbuf);

    for (int i = 0; i < DEPTH; i++) {
        const float* nw   = norm_w + i * 192;
        const float* cwf  = conv_w + (size_t)i * 384 * 4;
        const float* cbf  = conv_b + (size_t)i * 384;
        const float* cwr  = conv_w_b + (size_t)i * 384 * 4;
        const float* cbr  = conv_b_b + (size_t)i * 384;
        const float* dpf  = dtproj_w + (size_t)i * 384 * 12;
        const float* dpr  = dtproj_w_b + (size_t)i * 384 * 12;
        const float* dbf  = dt_bias + (size_t)i * 384;
        const float* dbr  = dt_bias_b + (size_t)i * 384;
        const float* alf  = A_log + (size_t)i * 384 * 16;
        const float* alr  = A_log_b + (size_t)i * 384 * 16;
        const float* dsf  = Dskip + (size_t)i * 384;
        const float* dsr  = Dskip_b + (size_t)i * 384;

        addnorm_k<0><<<NTOK, 192, 0, stream>>>(res, hbuf, nw, hnb);
        gemm_bf16<1><<<dim3(12, 65, 1), 256, 0, stream>>>(hnb, hnb,
                                                          winb + (size_t)i * 768 * 192, winb + (size_t)i * 768 * 192,
                                                          xzb, xzb, NTOK, 768, 192, 768);
        conv_silu_k<<<dim3(SEQL, BATCH, 2), 384, 0, stream>>>(xzb, cwf, cbf, cwr, cbr, xcfb, xcrb);
        gemm_bf16<0><<<dim3(1, 65, 2), 256, 0, stream>>>(xcfb, xcrb,
                                                         xpfb + (size_t)i * 44 * 384, xprb + (size_t)i * 44 * 384,
                                                         dtbcf, dtbcr, NTOK, 44, 384, 44);
        gemm_dt<<<dim3(6, 129, 2), 256, 0, stream>>>(dtbcf, dtbcr, 44, dpf, dpr, 12,
                                                     dtf, dtr, 384, NTOK, 384, 12, dbf, dbr);
        scan_p1<<<dim3(6 * NC, BATCH, 2), 64, 0, stream>>>(dtf, dtr, xcfb, xcrb, dtbcf, dtbcr,
                                                           alf, alr, Sbuf, sumdt);
        scan_mid<<<(BATCH * 2 * 384 * 16) / 256, 256, 0, stream>>>(Sbuf, sumdt, alf, alr);
        scan_p3<<<dim3(6 * NC, BATCH, 2), 64, 0, stream>>>(dtf, dtr, xcfb, xcrb, dtbcf, dtbcr, xzb,
                                                           alf, alr, dsf, dsr, Sbuf, ybf, ybr);
        gemm_out<<<dim3(3, 65, 1), 256, 0, stream>>>(ybf, ybr, woutb + (size_t)i * 192 * 384, hbuf,
                                                     NTOK, 192, 384, 192);
    }

    addnorm_k<1><<<NTOK, 192, 0, stream>>>(res, hbuf, norm_f_w, (float*)d_out);
}

// Round 5
// 4005.803 us; speedup vs baseline: 1.9839x; 1.0723x over previous
//
#include <hip/hip_runtime.h>
#include <hip/hip_bf16.h>
#include <math.h>

#define D_MODEL 192
#define D_INNER 384
#define D_STATE 16
#define DT_RANK 12
#define DEPTH   24
#define SEQL    257
#define BATCH   32
#define NTOK    (BATCH*SEQL)   // 8224
#define NC      8              // sequence chunks for the scan
#define CL      33             // chunk length (8*33 = 264 >= 257)
#define CCH     32             // conv chunk

typedef unsigned short ushort_t;
using bf16x8 = __attribute__((ext_vector_type(8))) short;
using f32x4  = __attribute__((ext_vector_type(4))) float;

__device__ __forceinline__ ushort_t f2b(float f) {
    __hip_bfloat16 h = __float2bfloat16(f);
    return reinterpret_cast<ushort_t&>(h);
}
__device__ __forceinline__ float b2f(ushort_t u) {
    __hip_bfloat16 h;
    reinterpret_cast<ushort_t&>(h) = u;
    return __bfloat162float(h);
}
__device__ __forceinline__ float softplus_f(float v) {
    return (v > 20.f) ? v : log1pf(expf(v));
}

// ---------------- fp32 -> bf16 conversion ----------------
__global__ __launch_bounds__(256) void convert_k(const float* __restrict__ in, ushort_t* __restrict__ out, int n) {
    int i = (blockIdx.x * 256 + threadIdx.x) * 4;
    if (i + 3 < n) {
        float4 v = *(const float4*)(in + i);
        ushort4 o;
        o.x = f2b(v.x); o.y = f2b(v.y); o.z = f2b(v.z); o.w = f2b(v.w);
        *(ushort4*)(out + i) = o;
    } else {
        for (int j = i; j < n; j++) out[j] = f2b(in[j]);
    }
}

// ---------------- patch rearrange: x (B,3,256,256) -> Apatch bf16 (B*256, 768) ----------------
__global__ __launch_bounds__(256) void rearrange_k(const float* __restrict__ x, ushort_t* __restrict__ Ap) {
    size_t i = (size_t)blockIdx.x * 256 + threadIdx.x;
    const size_t total = (size_t)8192 * 768 / 4;
    if (i >= total) return;
    size_t o = i * 4;
    int bt  = (int)(o / 768);
    int rem = (int)(o % 768);
    int c  = rem >> 8;
    int r2 = rem & 255;
    int pi = r2 >> 4;
    int pj = r2 & 15;
    int b = bt >> 8;
    int t = bt & 255;
    int ph = t >> 4, pw = t & 15;
    size_t src = (((size_t)(b * 3 + c) * 256) + (size_t)(ph * 16 + pi)) * 256 + (pw * 16 + pj);
    float4 v = *(const float4*)(x + src);
    ushort4 ov;
    ov.x = f2b(v.x); ov.y = f2b(v.y); ov.z = f2b(v.z); ov.w = f2b(v.w);
    *(ushort4*)(Ap + o) = ov;
}

// ---------------- assemble: insert cls token, add patch bias + pos embed ----------------
__global__ __launch_bounds__(192) void assemble_k(const float* __restrict__ P, const float* __restrict__ pb,
                                                  const float* __restrict__ cls, const float* __restrict__ pos,
                                                  float* __restrict__ hb) {
    int o = threadIdx.x;
    int l = blockIdx.x;
    int b = blockIdx.y;
    float v;
    if (l == 128) {
        v = cls[o];
    } else {
        int t = (l < 128) ? l : l - 1;
        v = P[((size_t)b * 256 + t) * 192 + o] + pb[o];
    }
    hb[((size_t)b * SEQL + l) * 192 + o] = v + pos[l * 192 + o];
}

// ---------------- fused add + RMSNorm ----------------
template<int FINAL>
__global__ __launch_bounds__(192) void addnorm_k(float* res, const float* __restrict__ h,
                                                 const float* __restrict__ w, void* __restrict__ outp) {
    int row = blockIdx.x;
    int t = threadIdx.x;
    size_t idx = (size_t)row * 192 + t;
    float r = res[idx] + h[idx];
    if (!FINAL) res[idx] = r;
    float ss = r * r;
    #pragma unroll
    for (int o = 32; o > 0; o >>= 1) ss += __shfl_down(ss, o);
    __shared__ float ps[3];
    int wid = t >> 6;
    if ((t & 63) == 0) ps[wid] = ss;
    __syncthreads();
    float tot = ps[0] + ps[1] + ps[2];
    float inv = rsqrtf(tot / 192.f + 1e-5f);
    float v = r * inv * w[t];
    if (FINAL) ((float*)outp)[idx] = v;
    else       ((ushort_t*)outp)[idx] = f2b(v);
}

// ---------------- bf16 MFMA GEMM, BM=128/BN=64: C[M,N] = A[M,K] * W[N,K]^T ----------------
template<int OUTBF>
__global__ __launch_bounds__(256) void gemm_bf16(const ushort_t* __restrict__ A,
                                                 const ushort_t* __restrict__ W,
                                                 void* __restrict__ C,
                                                 int M, int N, int K, int ldc) {
    __shared__ ushort_t As[128 * 40];
    __shared__ ushort_t Bs[64 * 40];
    int tid = threadIdx.x;
    int m0 = blockIdx.y * 128, n0 = blockIdx.x * 64;
    int row = tid >> 2;
    int k8  = (tid & 3) * 8;
    int lane = tid & 63;
    int w = tid >> 6;
    int wr = w >> 1, wc = w & 1;
    int lr = lane & 15;
    int lk = (lane >> 4) * 8;
    f32x4 acc[4][2];
    #pragma unroll
    for (int i = 0; i < 4; i++)
        #pragma unroll
        for (int j = 0; j < 2; j++) acc[i][j] = (f32x4){0.f, 0.f, 0.f, 0.f};

    for (int k0 = 0; k0 < K; k0 += 32) {
        #pragma unroll
        for (int hhalf = 0; hhalf < 2; hhalf++) {
            int r = row + hhalf * 64;
            int m = m0 + r;
            bf16x8 v = {0,0,0,0,0,0,0,0};
            if (m < M) v = *(const bf16x8*)(A + (size_t)m * K + k0 + k8);
            *(bf16x8*)(&As[r * 40 + k8]) = v;
        }
        {
            int n = n0 + row;
            bf16x8 v = {0,0,0,0,0,0,0,0};
            if (n < N) v = *(const bf16x8*)(W + (size_t)n * K + k0 + k8);
            *(bf16x8*)(&Bs[row * 40 + k8]) = v;
        }
        __syncthreads();
        bf16x8 af[4], bfr[2];
        #pragma unroll
        for (int mi = 0; mi < 4; mi++)
            af[mi] = *(const bf16x8*)(&As[(wr * 64 + mi * 16 + lr) * 40 + lk]);
        #pragma unroll
        for (int ni = 0; ni < 2; ni++)
            bfr[ni] = *(const bf16x8*)(&Bs[(wc * 32 + ni * 16 + lr) * 40 + lk]);
        #pragma unroll
        for (int mi = 0; mi < 4; mi++)
            #pragma unroll
            for (int ni = 0; ni < 2; ni++)
                acc[mi][ni] = __builtin_amdgcn_mfma_f32_16x16x32_bf16(af[mi], bfr[ni], acc[mi][ni], 0, 0, 0);
        __syncthreads();
    }
    int rbase = (lane >> 4) * 4;
    #pragma unroll
    for (int mi = 0; mi < 4; mi++) {
        #pragma unroll
        for (int ni = 0; ni < 2; ni++) {
            #pragma unroll
            for (int r = 0; r < 4; r++) {
                int m = m0 + wr * 64 + mi * 16 + rbase + r;
                int n = n0 + wc * 32 + ni * 16 + lr;
                if (m < M && n < N) {
                    if (OUTBF) ((ushort_t*)C)[(size_t)m * ldc + n] = f2b(acc[mi][ni][r]);
                    else       ((float*)C)[(size_t)m * ldc + n] = acc[mi][ni][r];
                }
            }
        }
    }
}

// ---------------- bf16 MFMA GEMM, BM=64/BN=64, dual-dir (xproj) ----------------
__global__ __launch_bounds__(256) void gemm_xproj(const ushort_t* __restrict__ A0, const ushort_t* __restrict__ A1,
                                                  const ushort_t* __restrict__ W0, const ushort_t* __restrict__ W1,
                                                  float* __restrict__ C0, float* __restrict__ C1,
                                                  int M, int N, int K, int ldc) {
    __shared__ ushort_t As[64 * 40];
    __shared__ ushort_t Bs[64 * 40];
    int dir = blockIdx.z;
    const ushort_t* A = dir ? A1 : A0;
    const ushort_t* W = dir ? W1 : W0;
    float* C = dir ? C1 : C0;
    int tid = threadIdx.x;
    int m0 = blockIdx.y * 64, n0 = blockIdx.x * 64;
    int row = tid >> 2;
    int k8  = (tid & 3) * 8;
    int lane = tid & 63;
    int w = tid >> 6;
    int wr = w >> 1, wc = w & 1;
    int lr = lane & 15;
    int lk = (lane >> 4) * 8;
    f32x4 acc[2][2];
    #pragma unroll
    for (int i = 0; i < 2; i++)
        #pragma unroll
        for (int j = 0; j < 2; j++) acc[i][j] = (f32x4){0.f, 0.f, 0.f, 0.f};

    for (int k0 = 0; k0 < K; k0 += 32) {
        {
            int m = m0 + row;
            bf16x8 v = {0,0,0,0,0,0,0,0};
            if (m < M) v = *(const bf16x8*)(A + (size_t)m * K + k0 + k8);
            *(bf16x8*)(&As[row * 40 + k8]) = v;
            int n = n0 + row;
            bf16x8 wv = {0,0,0,0,0,0,0,0};
            if (n < N) wv = *(const bf16x8*)(W + (size_t)n * K + k0 + k8);
            *(bf16x8*)(&Bs[row * 40 + k8]) = wv;
        }
        __syncthreads();
        bf16x8 af[2], bfr[2];
        #pragma unroll
        for (int mi = 0; mi < 2; mi++)
            af[mi] = *(const bf16x8*)(&As[(wr * 32 + mi * 16 + lr) * 40 + lk]);
        #pragma unroll
        for (int ni = 0; ni < 2; ni++)
            bfr[ni] = *(const bf16x8*)(&Bs[(wc * 32 + ni * 16 + lr) * 40 + lk]);
        #pragma unroll
        for (int mi = 0; mi < 2; mi++)
            #pragma unroll
            for (int ni = 0; ni < 2; ni++)
                acc[mi][ni] = __builtin_amdgcn_mfma_f32_16x16x32_bf16(af[mi], bfr[ni], acc[mi][ni], 0, 0, 0);
        __syncthreads();
    }
    int rbase = (lane >> 4) * 4;
    #pragma unroll
    for (int mi = 0; mi < 2; mi++) {
        #pragma unroll
        for (int ni = 0; ni < 2; ni++) {
            #pragma unroll
            for (int r = 0; r < 4; r++) {
                int m = m0 + wr * 32 + mi * 16 + rbase + r;
                int n = n0 + wc * 32 + ni * 16 + lr;
                if (m < M && n < N) C[(size_t)m * ldc + n] = acc[mi][ni][r];
            }
        }
    }
}

// ---------------- out_proj GEMM BM=64 with fused direction-combine on A ----------------
__global__ __launch_bounds__(256) void gemm_out(const ushort_t* __restrict__ yf, const ushort_t* __restrict__ yr,
                                                const ushort_t* __restrict__ W, float* __restrict__ C,
                                                int M, int N, int K, int ldc) {
    __shared__ ushort_t As[64 * 40];
    __shared__ ushort_t Bs[64 * 40];
    int tid = threadIdx.x;
    int m0 = blockIdx.y * 64, n0 = blockIdx.x * 64;
    int row = tid >> 2;
    int k8  = (tid & 3) * 8;
    int lane = tid & 63;
    int w = tid >> 6;
    int wr = w >> 1, wc = w & 1;
    int lr = lane & 15;
    int lk = (lane >> 4) * 8;
    int m_ld = m0 + row;
    int mok = (m_ld < M);
    int bb = m_ld / SEQL;
    int ll = m_ld - bb * SEQL;
    size_t rowf = (size_t)m_ld * 384;
    size_t rowr = ((size_t)bb * SEQL + (SEQL - 1 - ll)) * 384;
    f32x4 acc[2][2];
    #pragma unroll
    for (int i = 0; i < 2; i++)
        #pragma unroll
        for (int j = 0; j < 2; j++) acc[i][j] = (f32x4){0.f, 0.f, 0.f, 0.f};

    for (int k0 = 0; k0 < K; k0 += 32) {
        {
            bf16x8 v = {0,0,0,0,0,0,0,0};
            if (mok) {
                bf16x8 vf = *(const bf16x8*)(yf + rowf + k0 + k8);
                bf16x8 vr = *(const bf16x8*)(yr + rowr + k0 + k8);
                #pragma unroll
                for (int j = 0; j < 8; j++) {
                    float a = b2f((ushort_t)vf[j]);
                    float b2 = b2f((ushort_t)vr[j]);
                    v[j] = (short)f2b(0.5f * (a + b2));
                }
            }
            *(bf16x8*)(&As[row * 40 + k8]) = v;
            int n = n0 + row;
            bf16x8 wv = {0,0,0,0,0,0,0,0};
            if (n < N) wv = *(const bf16x8*)(W + (size_t)n * K + k0 + k8);
            *(bf16x8*)(&Bs[row * 40 + k8]) = wv;
        }
        __syncthreads();
        bf16x8 af[2], bfr[2];
        #pragma unroll
        for (int mi = 0; mi < 2; mi++)
            af[mi] = *(const bf16x8*)(&As[(wr * 32 + mi * 16 + lr) * 40 + lk]);
        #pragma unroll
        for (int ni = 0; ni < 2; ni++)
            bfr[ni] = *(const bf16x8*)(&Bs[(wc * 32 + ni * 16 + lr) * 40 + lk]);
        #pragma unroll
        for (int mi = 0; mi < 2; mi++)
            #pragma unroll
            for (int ni = 0; ni < 2; ni++)
                acc[mi][ni] = __builtin_amdgcn_mfma_f32_16x16x32_bf16(af[mi], bfr[ni], acc[mi][ni], 0, 0, 0);
        __syncthreads();
    }
    int rbase = (lane >> 4) * 4;
    #pragma unroll
    for (int mi = 0; mi < 2; mi++) {
        #pragma unroll
        for (int ni = 0; ni < 2; ni++) {
            #pragma unroll
            for (int r = 0; r < 4; r++) {
                int m = m0 + wr * 32 + mi * 16 + rbase + r;
                int n = n0 + wc * 32 + ni * 16 + lr;
                if (m < M && n < N) C[(size_t)m * ldc + n] = acc[mi][ni][r];
            }
        }
    }
}

// ---------------- causal depthwise conv (k=4) + SiLU, rolling window, both dirs ----------------
__global__ __launch_bounds__(384) void conv_silu_k(const ushort_t* __restrict__ xz,
                                                   const float* __restrict__ cw, const float* __restrict__ cb,
                                                   const float* __restrict__ cwb, const float* __restrict__ cbb,
                                                   ushort_t* __restrict__ xcf, ushort_t* __restrict__ xcr) {
    int d = threadIdx.x;
    int lc = blockIdx.x;
    int b = blockIdx.y;
    int dir = blockIdx.z;
    int lstart = lc * CCH;
    int lend = (lstart + CCH < SEQL) ? (lstart + CCH) : SEQL;
    const float* w = dir ? cwb : cw;
    const float* bias = dir ? cbb : cb;
    float4 wv = *(const float4*)(w + d * 4);
    float bs = bias[d];
    ushort_t* out = dir ? xcr : xcf;
    size_t base = (size_t)b * SEQL;
    // xin[j] = xz[b, dir? 256-j : j, d]
    float win0 = 0.f, win1 = 0.f, win2 = 0.f;
    if (lstart - 3 >= 0) win0 = b2f(xz[(base + (dir ? (SEQL-1-(lstart-3)) : (lstart-3))) * 768 + d]);
    if (lstart - 2 >= 0) win1 = b2f(xz[(base + (dir ? (SEQL-1-(lstart-2)) : (lstart-2))) * 768 + d]);
    if (lstart - 1 >= 0) win2 = b2f(xz[(base + (dir ? (SEQL-1-(lstart-1)) : (lstart-1))) * 768 + d]);
    float xcur = b2f(xz[(base + (dir ? (SEQL-1-lstart) : lstart)) * 768 + d]);
    for (int l = lstart; l < lend; l++) {
        int ln = l + 1;
        float xnext = 0.f;
        if (ln < lend) xnext = b2f(xz[(base + (dir ? (SEQL-1-ln) : ln)) * 768 + d]);
        float a = bs;
        a = fmaf(wv.x, win0, a);
        a = fmaf(wv.y, win1, a);
        a = fmaf(wv.z, win2, a);
        a = fmaf(wv.w, xcur, a);
        float s = a / (1.f + __expf(-a));
        out[(base + l) * 384 + d] = f2b(s);
        win0 = win1; win1 = win2; win2 = xcur; xcur = xnext;
    }
}

// ============ chunked selective scan (dt fused) ============
// pass 1: per chunk, from h=0 compute S[16] + sum(dt). dt = softplus(dtlo·dtw + bias).
__global__ __launch_bounds__(64) void scan_p1(const ushort_t* __restrict__ xcf, const ushort_t* __restrict__ xcr,
                                              const float* __restrict__ dtbcf, const float* __restrict__ dtbcr,
                                              const float* __restrict__ dwf, const float* __restrict__ dwr,
                                              const float* __restrict__ dbf, const float* __restrict__ dbr,
                                              const float* __restrict__ Alf, const float* __restrict__ Alb,
                                              float* __restrict__ Sbuf, float* __restrict__ sumdt) {
    __shared__ float rows[CL * 44];
    int tid = threadIdx.x;
    int dchunk = blockIdx.x % 6, c = blockIdx.x / 6;
    int d = dchunk * 64 + tid;
    int b = blockIdx.y, dir = blockIdx.z;
    int bd = b * 2 + dir;
    const ushort_t* xcp = dir ? xcr : xcf;
    const float* pbc = (dir ? dtbcr : dtbcf) + (size_t)b * SEQL * 44;
    int lstart = c * CL;
    int clen = (lstart + CL < SEQL) ? CL : (SEQL - lstart);

    for (int i = tid; i < clen * 11; i += 64) {
        int l = i / 11, j = i - l * 11;
        *(float4*)(&rows[l * 44 + j * 4]) = *(const float4*)(pbc + (size_t)(lstart + l) * 44 + j * 4);
    }
    __syncthreads();

    float dw[12];
    {
        const float* dwp = (dir ? dwr : dwf) + d * 12;
        #pragma unroll
        for (int r = 0; r < 12; r++) dw[r] = dwp[r];
    }
    float dbias = (dir ? dbr : dbf)[d];
    const float* alog = (dir ? Alb : Alf) + d * 16;
    float A[16];
    #pragma unroll
    for (int n = 0; n < 16; n++) A[n] = -__expf(alog[n]);
    float S[16];
    #pragma unroll
    for (int n = 0; n < 16; n++) S[n] = 0.f;
    float ssum = 0.f;

    size_t rowbase = (size_t)b * SEQL + lstart;
    float x_c = b2f(xcp[rowbase * 384 + d]);
    for (int l = 0; l < clen; l++) {
        int ln = (l + 1 < clen) ? (l + 1) : l;
        float x_n = b2f(xcp[(rowbase + ln) * 384 + d]);
        const float* rw = &rows[l * 44];
        float av = dbias;
        #pragma unroll
        for (int r = 0; r < 12; r++) av = fmaf(rw[r], dw[r], av);
        float dt = softplus_f(av);
        ssum += dt;
        float dtx = dt * x_c;
        #pragma unroll
        for (int n = 0; n < 16; n++)
            S[n] = fmaf(S[n], __expf(dt * A[n]), dtx * rw[12 + n]);
        x_c = x_n;
    }
    float* sp = Sbuf + ((size_t)bd * NC + c) * 6144 + d * 16;
    #pragma unroll
    for (int j = 0; j < 4; j++)
        *(float4*)(sp + j * 4) = make_float4(S[j*4], S[j*4+1], S[j*4+2], S[j*4+3]);
    sumdt[((size_t)bd * NC + c) * 384 + d] = ssum;
}

// pass 3: prefix from Sbuf/sumdt in prologue, then re-scan chunk, emit y*silu(z) bf16.
__global__ __launch_bounds__(64) void scan_p3(const ushort_t* __restrict__ xcf, const ushort_t* __restrict__ xcr,
                                              const float* __restrict__ dtbcf, const float* __restrict__ dtbcr,
                                              const float* __restrict__ dwf, const float* __restrict__ dwr,
                                              const float* __restrict__ dbf, const float* __restrict__ dbr,
                                              const float* __restrict__ Alf, const float* __restrict__ Alb,
                                              const float* __restrict__ Df, const float* __restrict__ Db,
                                              const ushort_t* __restrict__ xz,
                                              const float* __restrict__ Sbuf, const float* __restrict__ sumdt,
                                              ushort_t* __restrict__ ybf, ushort_t* __restrict__ ybr) {
    __shared__ float rows[CL * 44];
    int tid = threadIdx.x;
    int dchunk = blockIdx.x % 6, c = blockIdx.x / 6;
    int d = dchunk * 64 + tid;
    int b = blockIdx.y, dir = blockIdx.z;
    int bd = b * 2 + dir;
    const ushort_t* xcp = dir ? xcr : xcf;
    const float* pbc = (dir ? dtbcr : dtbcf) + (size_t)b * SEQL * 44;
    ushort_t* yb = dir ? ybr : ybf;
    int lstart = c * CL;
    int clen = (lstart + CL < SEQL) ? CL : (SEQL - lstart);

    for (int i = tid; i < clen * 11; i += 64) {
        int l = i / 11, j = i - l * 11;
        *(float4*)(&rows[l * 44 + j * 4]) = *(const float4*)(pbc + (size_t)(lstart + l) * 44 + j * 4);
    }
    __syncthreads();

    float dw[12];
    {
        const float* dwp = (dir ? dwr : dwf) + d * 12;
        #pragma unroll
        for (int r = 0; r < 12; r++) dw[r] = dwp[r];
    }
    float dbias = (dir ? dbr : dbf)[d];
    const float* alog = (dir ? Alb : Alf) + d * 16;
    float A[16], h[16];
    #pragma unroll
    for (int n = 0; n < 16; n++) { A[n] = -__expf(alog[n]); h[n] = 0.f; }

    // prefix over earlier chunks (replaces scan_mid)
    for (int cp = 0; cp < c; cp++) {
        float sd = sumdt[((size_t)bd * NC + cp) * 384 + d];
        const float4* sp = (const float4*)(Sbuf + ((size_t)bd * NC + cp) * 6144 + d * 16);
        #pragma unroll
        for (int j = 0; j < 4; j++) {
            float4 sv = sp[j];
            h[j*4+0] = fmaf(h[j*4+0], __expf(A[j*4+0] * sd), sv.x);
            h[j*4+1] = fmaf(h[j*4+1], __expf(A[j*4+1] * sd), sv.y);
            h[j*4+2] = fmaf(h[j*4+2], __expf(A[j*4+2] * sd), sv.z);
            h[j*4+3] = fmaf(h[j*4+3], __expf(A[j*4+3] * sd), sv.w);
        }
    }
    float Dp = (dir ? Db : Df)[d];

    size_t rowbase = (size_t)b * SEQL + lstart;
    size_t seqbase = (size_t)b * SEQL;
    float x_c = b2f(xcp[rowbase * 384 + d]);
    float z_c = b2f(xz[(dir ? (seqbase + SEQL - 1 - lstart) : rowbase) * 768 + 384 + d]);
    for (int l = 0; l < clen; l++) {
        int ln = (l + 1 < clen) ? (l + 1) : l;
        float x_n = b2f(xcp[(rowbase + ln) * 384 + d]);
        float z_n = b2f(xz[(dir ? (seqbase + SEQL - 1 - (lstart + ln)) : (rowbase + ln)) * 768 + 384 + d]);

        const float* rw = &rows[l * 44];
        float av = dbias;
        #pragma unroll
        for (int r = 0; r < 12; r++) av = fmaf(rw[r], dw[r], av);
        float dt = softplus_f(av);
        float dtx = dt * x_c;
        float y = 0.f;
        #pragma unroll
        for (int n = 0; n < 16; n++) {
            h[n] = fmaf(h[n], __expf(dt * A[n]), dtx * rw[12 + n]);
            y = fmaf(h[n], rw[28 + n], y);
        }
        y = fmaf(Dp, x_c, y);
        float sz = z_c / (1.f + __expf(-z_c));
        yb[(rowbase + l) * 384 + d] = f2b(y * sz);
        x_c = x_n; z_c = z_n;
    }
}

extern "C" void kernel_launch(void* const* d_in, const int* in_sizes, int n_in,
                              void* d_out, int out_size, void* d_ws, size_t ws_size,
                              hipStream_t stream) {
    const float* x         = (const float*)d_in[0];
    const float* patch_w   = (const float*)d_in[1];
    const float* patch_b   = (const float*)d_in[2];
    const float* cls_token = (const float*)d_in[3];
    const float* pos_embed = (const float*)d_in[4];
    const float* norm_w    = (const float*)d_in[5];
    const float* in_proj_w = (const float*)d_in[6];
    const float* conv_w    = (const float*)d_in[7];
    const float* conv_b    = (const float*)d_in[8];
    const float* xproj_w   = (const float*)d_in[9];
    const float* dtproj_w  = (const float*)d_in[10];
    const float* dt_bias   = (const float*)d_in[11];
    const float* A_log     = (const float*)d_in[12];
    const float* Dskip     = (const float*)d_in[13];
    const float* conv_w_b  = (const float*)d_in[14];
    const float* conv_b_b  = (const float*)d_in[15];
    const float* xproj_w_b = (const float*)d_in[16];
    const float* dtproj_w_b= (const float*)d_in[17];
    const float* dt_bias_b = (const float*)d_in[18];
    const float* A_log_b   = (const float*)d_in[19];
    const float* Dskip_b   = (const float*)d_in[20];
    const float* out_proj_w= (const float*)d_in[21];
    const float* norm_f_w  = (const float*)d_in[22];

    float* ws = (float*)d_ws;
    size_t off = 0;
    float* res   = ws + off; off += (size_t)NTOK * 192;
    float* hbuf  = ws + off; off += (size_t)NTOK * 192;
    ushort_t* xzb = (ushort_t*)(ws + off); off += (size_t)NTOK * 384;   // NTOK*768 ushorts; also Apatch
    ushort_t* hnb = (ushort_t*)(ws + off); off += (size_t)NTOK * 96;
    ushort_t* xcfb = (ushort_t*)(ws + off); off += (size_t)NTOK * 192;
    ushort_t* xcrb = (ushort_t*)(ws + off); off += (size_t)NTOK * 192;
    float* dtbcf = ws + off; off += (size_t)NTOK * 44;
    float* dtbcr = ws + off; off += (size_t)NTOK * 44;
    ushort_t* ybf = (ushort_t*)(ws + off); off += (size_t)NTOK * 192;
    ushort_t* ybr = (ushort_t*)(ws + off); off += (size_t)NTOK * 192;
    float* Sbuf  = ws + off; off += (size_t)BATCH * 2 * NC * 6144;      // also Ppatch fp32
    float* sumdt = ws + off; off += (size_t)BATCH * 2 * NC * 384;
    ushort_t* wb = (ushort_t*)(ws + off);
    ushort_t* winb   = wb;
    ushort_t* woutb  = winb  + 3538944;
    ushort_t* xpfb   = woutb + 1769472;
    ushort_t* xprb   = xpfb  + 405504;
    ushort_t* patchwb= xprb  + 405504;

    ushort_t* Apatch = xzb;
    float* Ppatch = Sbuf;

    convert_k<<<(3538944/4 + 255)/256, 256, 0, stream>>>(in_proj_w, winb, 3538944);
    convert_k<<<(1769472/4 + 255)/256, 256, 0, stream>>>(out_proj_w, woutb, 1769472);
    convert_k<<<(405504/4 + 255)/256, 256, 0, stream>>>(xproj_w, xpfb, 405504);
    convert_k<<<(405504/4 + 255)/256, 256, 0, stream>>>(xproj_w_b, xprb, 405504);
    convert_k<<<(147456/4 + 255)/256, 256, 0, stream>>>(patch_w, patchwb, 147456);

    hipMemsetAsync(res, 0, (size_t)NTOK * 192 * sizeof(float), stream);

    rearrange_k<<<6144, 256, 0, stream>>>(x, Apatch);
    gemm_bf16<0><<<dim3(3, 64), 256, 0, stream>>>(Apatch, patchwb, Ppatch, 8192, 192, 768, 192);
    assemble_k<<<dim3(SEQL, BATCH), 192, 0, stream>>>(Ppatch, patch_b, cls_token, pos_embed, hbuf);

    for (int i = 0; i < DEPTH; i++) {
        const float* nw   = norm_w + i * 192;
        const float* cwf  = conv_w + (size_t)i * 384 * 4;
        const float* cbf  = conv_b + (size_t)i * 384;
        const float* cwr  = conv_w_b + (size_t)i * 384 * 4;
        const float* cbr  = conv_b_b + (size_t)i * 384;
        const float* dpf  = dtproj_w + (size_t)i * 384 * 12;
        const float* dpr  = dtproj_w_b + (size_t)i * 384 * 12;
        const float* dbf  = dt_bias + (size_t)i * 384;
        const float* dbr  = dt_bias_b + (size_t)i * 384;
        const float* alf  = A_log + (size_t)i * 384 * 16;
        const float* alr  = A_log_b + (size_t)i * 384 * 16;
        const float* dsf  = Dskip + (size_t)i * 384;
        const float* dsr  = Dskip_b + (size_t)i * 384;

        addnorm_k<0><<<NTOK, 192, 0, stream>>>(res, hbuf, nw, hnb);
        gemm_bf16<1><<<dim3(12, 65), 256, 0, stream>>>(hnb, winb + (size_t)i * 768 * 192, xzb,
                                                       NTOK, 768, 192, 768);
        conv_silu_k<<<dim3((SEQL + CCH - 1) / CCH, BATCH, 2), 384, 0, stream>>>(xzb, cwf, cbf, cwr, cbr, xcfb, xcrb);
        gemm_xproj<<<dim3(1, 129, 2), 256, 0, stream>>>(xcfb, xcrb,
                                                        xpfb + (size_t)i * 44 * 384, xprb + (size_t)i * 44 * 384,
                                                        dtbcf, dtbcr, NTOK, 44, 384, 44);
        scan_p1<<<dim3(6 * NC, BATCH, 2), 64, 0, stream>>>(xcfb, xcrb, dtbcf, dtbcr,
                                                           dpf, dpr, dbf, dbr, alf, alr, Sbuf, sumdt);
        scan_p3<<<dim3(6 * NC, BATCH, 2), 64, 0, stream>>>(xcfb, xcrb, dtbcf, dtbcr,
                                                           dpf, dpr, dbf, dbr, alf, alr, dsf, dsr,
                                                           xzb, Sbuf, sumdt, ybf, ybr);
        gemm_out<<<dim3(3, 129), 256, 0, stream>>>(ybf, ybr, woutb + (size_t)i * 192 * 384, hbuf,
                                                   NTOK, 192, 384, 192);
    }

    addnorm_k<1><<<NTOK, 192, 0, stream>>>(res, hbuf, norm_f_w, (float*)d_out);
}